// Round 4
// baseline (2766.735 us; speedup 1.0000x reference)
//
#include <hip/hip_runtime.h>
#include <hip/hip_bf16.h>
#include <stdint.h>

#define NROWS 12288
#define DIM   512
#define KNBR  10

// gram_topk geometry
#define NC    8            // column chunks
#define CHUNK (NROWS / NC) // 1536
#define BM    128
#define BN    128
#define BK    32
#define CT    (CHUNK / BN) // 12 col-tiles per block

typedef __attribute__((ext_vector_type(8))) short s16x8;
typedef __attribute__((ext_vector_type(4))) float f32x4;
typedef unsigned int u32;

static __device__ __forceinline__ unsigned short f2bf(float x) {
  __hip_bfloat16 b = __float2bfloat16(x);
  return *reinterpret_cast<unsigned short*>(&b);
}

static __device__ __forceinline__ void gload16(const void* g, void* l) {
  __builtin_amdgcn_global_load_lds(
      (const __attribute__((address_space(1))) u32*)g,
      (__attribute__((address_space(3))) u32*)l, 16, 0, 0);
}

// Stable top-k insert: keeps list sorted by (value desc, index asc).
#define TOPK_INSERT(TV, TI, V, IDX)                                              \
  do {                                                                           \
    float _v = (V); int _i = (IDX);                                              \
    if (_v > TV[9] || (_v == TV[9] && _i < TI[9])) {                             \
      TV[9] = _v; TI[9] = _i;                                                    \
      _Pragma("unroll")                                                          \
      for (int _s = 9; _s > 0; --_s) {                                           \
        bool _sw = (TV[_s] > TV[_s-1]) ||                                        \
                   (TV[_s] == TV[_s-1] && TI[_s] < TI[_s-1]);                    \
        if (_sw) {                                                               \
          float _tf = TV[_s]; TV[_s] = TV[_s-1]; TV[_s-1] = _tf;                 \
          int   _ti = TI[_s]; TI[_s] = TI[_s-1]; TI[_s-1] = _ti;                 \
        }                                                                        \
      }                                                                          \
    }                                                                            \
  } while (0)

// ---------------- Kernel 1: norms + bf16 conversion ----------------
__global__ __launch_bounds__(256) void prep_kernel(
    const float* __restrict__ f, float* __restrict__ sq,
    unsigned short* __restrict__ fbf) {
  const int wid = threadIdx.x >> 6;
  const int lane = threadIdx.x & 63;
  const int row = blockIdx.x * 4 + wid;
  const float4* fr = (const float4*)(f + (size_t)row * DIM);
  ushort4* br = (ushort4*)(fbf + (size_t)row * DIM);
  float s = 0.f;
#pragma unroll
  for (int u = 0; u < 2; ++u) {
    float4 v = fr[u * 64 + lane];
    s += v.x * v.x + v.y * v.y + v.z * v.z + v.w * v.w;
    ushort4 h;
    h.x = f2bf(v.x); h.y = f2bf(v.y); h.z = f2bf(v.z); h.w = f2bf(v.w);
    br[u * 64 + lane] = h;
  }
#pragma unroll
  for (int off = 32; off; off >>= 1) s += __shfl_down(s, off);
  if (lane == 0) sq[row] = s;
}

// ---------------- Kernel 2: 128x128 MFMA gram + chunked top-10 ----------------
// grid (96, NC). Block (rt, ch): rows rt*128..+128 x cols ch*CHUNK..+CHUNK.
// NOTE: __launch_bounds__(256) WITHOUT a min-waves clause. (256,3) capped the
// allocator at ~168 VGPR and demoted the 64-VGPR f32x4 acc[4][4] to scratch:
// VGPR_Count=84 and 9.3 GB of scratch WRITE_SIZE in rounds 2-3.
__global__ __launch_bounds__(256) void gram_topk(
    const unsigned short* __restrict__ fbf, const float* __restrict__ sq,
    float2* __restrict__ part, float* __restrict__ out) {
  // LDS: [0,8192) A [4][128][8] bf16 ; [8192,16384) B ; [16384,+16768) slab [32][131] f32
  __shared__ __align__(16) char smem[33152];
  __shared__ float sqr[BM];
  __shared__ float sqc[BN];

  const int t = threadIdx.x;
  const int lane = t & 63, wid = t >> 6;
  const int wr = wid >> 1, wc = wid & 1;     // wave -> 64x64 quadrant
  const int fr = lane & 15, kg = lane >> 4;  // MFMA fragment coords
  const int brow = blockIdx.x * BM;
  const int chunk = blockIdx.y;

  // Zero-fill this block's slice of the output.
  {
    const int bid = blockIdx.y * 96 + blockIdx.x;          // 0..767
    const int per = NROWS * NROWS / (96 * NC) / 4;         // f32x4 per block
    f32x4* o4 = (f32x4*)out + (size_t)bid * per;
    f32x4 z = {0.f, 0.f, 0.f, 0.f};
    for (int i = t; i < per; i += 256) o4[i] = z;
  }
  if (t < BM) sqr[t] = sq[brow + t];

  short* Abuf = (short*)smem;
  short* Bbuf = (short*)(smem + 8192);
  float* slab = (float*)(smem + 16384);

  // per-thread partial top-10: thread owns row rt2 = t>>1, col-half h = t&1
  float tv[10]; int ti[10];
#pragma unroll
  for (int s = 0; s < 10; ++s) { tv[s] = -INFINITY; ti[s] = 0x7fffffff; }
  const int rt2 = t >> 1, h = t & 1;
  const int mneed = (rt2 >> 4) & 3;
  const int srow = ((rt2 >> 6) << 4) + (rt2 & 15);

  for (int ct = 0; ct < CT; ++ct) {
    const int bcol = chunk * CHUNK + ct * BN;
    if (t < BN) sqc[t] = sq[bcol + t];   // covered by first K-step barrier

    f32x4 acc[4][4];
#pragma unroll
    for (int m = 0; m < 4; ++m)
#pragma unroll
      for (int n = 0; n < 4; ++n)
#pragma unroll
        for (int q = 0; q < 4; ++q) acc[m][n][q] = 0.f;

    for (int kt = 0; kt < DIM; kt += BK) {
      // stage A,B tiles: [4 kgroups][128 rows][8 bf16], 512x16B chunks each
#pragma unroll
      for (int i = 0; i < 2; ++i) {
        const int c = i * 256 + t;
        const int row = c & 127, ckg = c >> 7;
        gload16(&fbf[(size_t)(brow + row) * DIM + kt + ckg * 8],
                smem + (i * 256 + wid * 64) * 16);
        gload16(&fbf[(size_t)(bcol + row) * DIM + kt + ckg * 8],
                smem + 8192 + (i * 256 + wid * 64) * 16);
      }
      __syncthreads();

      s16x8 a[4], b[4];
#pragma unroll
      for (int m = 0; m < 4; ++m)
        a[m] = *(const s16x8*)&Abuf[(kg * 128 + wr * 64 + m * 16 + fr) * 8];
#pragma unroll
      for (int n = 0; n < 4; ++n)
        b[n] = *(const s16x8*)&Bbuf[(kg * 128 + wc * 64 + n * 16 + fr) * 8];
#pragma unroll
      for (int m = 0; m < 4; ++m)
#pragma unroll
        for (int n = 0; n < 4; ++n)
          acc[m][n] = __builtin_amdgcn_mfma_f32_16x16x32_bf16(a[m], b[n], acc[m][n], 0, 0, 0);
      __syncthreads();
    }

    // epilogue: 4 slabs of 32 rows x 128 cols; sim -> LDS -> stable scan.
#pragma unroll
    for (int m = 0; m < 4; ++m) {
#pragma unroll
      for (int n = 0; n < 4; ++n)
#pragma unroll
        for (int q = 0; q < 4; ++q) {
          const int rl = kg * 4 + q;            // 0..15 within band
          const int tr = wr * 64 + m * 16 + rl; // tile row
          const int tc = wc * 64 + n * 16 + fr; // tile col
          const float dist = sqr[tr] + sqc[tc] - 2.0f * acc[m][n][q];
          const float sv = ((brow + tr) == (bcol + tc)) ? 0.0f
                          : __expf(-fmaxf(dist, 0.0f));
          slab[(wr * 16 + rl) * 131 + tc] = sv;
        }
      __syncthreads();
      if (mneed == m) {
#pragma unroll
        for (int c = 0; c < 64; ++c) {
          const float v = slab[srow * 131 + h * 64 + c];
          TOPK_INSERT(tv, ti, v, bcol + h * 64 + c);
        }
      }
      __syncthreads();
    }
  }

  // merge the two half-lists per row, write chunk list to ws
  float2* plist = (float2*)smem;  // 256*10*8 = 20480 B, overlays dead A/B/slab
  __syncthreads();
#pragma unroll
  for (int s = 0; s < 10; ++s)
    plist[t * 10 + s] = make_float2(tv[s], __int_as_float(ti[s]));
  __syncthreads();
  if (t < BM) {
    float mv[10]; int mi[10];
#pragma unroll
    for (int s = 0; s < 10; ++s) { mv[s] = -INFINITY; mi[s] = 0x7fffffff; }
#pragma unroll
    for (int p = 0; p < 2; ++p)
#pragma unroll
      for (int s = 0; s < 10; ++s) {
        const float2 e = plist[(t * 2 + p) * 10 + s];
        TOPK_INSERT(mv, mi, e.x, __float_as_int(e.y));
      }
    float2* dst = part + ((size_t)(brow + t) * NC + chunk) * 10;
#pragma unroll
    for (int s = 0; s < 10; ++s) dst[s] = make_float2(mv[s], __int_as_float(mi[s]));
  }
}

// ---------------- Kernel 3: merge NC chunk lists per row, scatter ones ----------------
__global__ __launch_bounds__(256) void merge_scatter(
    const float2* __restrict__ part, float* __restrict__ out) {
  const int t = threadIdx.x;
  if (t >= 128) return;
  const int r = blockIdx.x * 128 + t;
  float mv[10]; int mi[10];
#pragma unroll
  for (int s = 0; s < 10; ++s) { mv[s] = -INFINITY; mi[s] = 0x7fffffff; }
  const float2* p = part + (size_t)r * NC * 10;
#pragma unroll
  for (int c = 0; c < NC * 10; ++c)
    TOPK_INSERT(mv, mi, p[c].x, __float_as_int(p[c].y));
  float* orow = out + (size_t)r * NROWS;
#pragma unroll
  for (int s = 0; s < 10; ++s) orow[mi[s]] = 1.0f;
}

// ---------------- Fallback (round-1 single-kernel path, needs only 12.6 MB ws) ----------------
__global__ __launch_bounds__(256) void knn_fallback(
    const unsigned short* __restrict__ fbf, const float* __restrict__ sq,
    float* __restrict__ out) {
  __shared__ short aT[64][32];
  __shared__ short bT[64][32];
  __shared__ float simf[5120];
  __shared__ float sqrow[64];

  const int t = threadIdx.x;
  const int lane = t & 63, wid = t >> 6;
  const int wr = wid >> 1, wc = wid & 1;
  const int fr = lane & 15, kg = lane >> 4;
  const int brow = blockIdx.x * 64;

  {
    f32x4* o4 = (f32x4*)(out + (size_t)brow * NROWS);
    const int total4 = 64 * NROWS / 4;
    f32x4 z = {0.f, 0.f, 0.f, 0.f};
    for (int i = t; i < total4; i += 256) o4[i] = z;
  }
  if (t < 64) sqrow[t] = sq[brow + t];

  float tv[10]; int ti[10];
#pragma unroll
  for (int s = 0; s < 10; ++s) { tv[s] = -INFINITY; ti[s] = 0x7fffffff; }
  const int sstage_r = t >> 2;
  const int sstage_k = (t & 3) * 8;

  for (int ctile = 0; ctile < NROWS / 64; ++ctile) {
    const int bcol = ctile * 64;
    f32x4 acc[2][2];
#pragma unroll
    for (int m = 0; m < 2; ++m)
#pragma unroll
      for (int n = 0; n < 2; ++n)
#pragma unroll
        for (int q = 0; q < 4; ++q) acc[m][n][q] = 0.f;

    for (int kt = 0; kt < DIM; kt += 32) {
      *(s16x8*)&aT[sstage_r][sstage_k] =
          *(const s16x8*)&fbf[(size_t)(brow + sstage_r) * DIM + kt + sstage_k];
      *(s16x8*)&bT[sstage_r][sstage_k] =
          *(const s16x8*)&fbf[(size_t)(bcol + sstage_r) * DIM + kt + sstage_k];
      __syncthreads();
      s16x8 a0 = *(const s16x8*)&aT[wr * 32 + fr][kg * 8];
      s16x8 a1 = *(const s16x8*)&aT[wr * 32 + 16 + fr][kg * 8];
      s16x8 b0 = *(const s16x8*)&bT[wc * 32 + fr][kg * 8];
      s16x8 b1 = *(const s16x8*)&bT[wc * 32 + 16 + fr][kg * 8];
      acc[0][0] = __builtin_amdgcn_mfma_f32_16x16x32_bf16(a0, b0, acc[0][0], 0, 0, 0);
      acc[0][1] = __builtin_amdgcn_mfma_f32_16x16x32_bf16(a0, b1, acc[0][1], 0, 0, 0);
      acc[1][0] = __builtin_amdgcn_mfma_f32_16x16x32_bf16(a1, b0, acc[1][0], 0, 0, 0);
      acc[1][1] = __builtin_amdgcn_mfma_f32_16x16x32_bf16(a1, b1, acc[1][1], 0, 0, 0);
      __syncthreads();
    }
#pragma unroll
    for (int m = 0; m < 2; ++m)
#pragma unroll
      for (int n = 0; n < 2; ++n)
#pragma unroll
        for (int q = 0; q < 4; ++q) {
          int rl = wr * 32 + m * 16 + kg * 4 + q;
          int cl = wc * 32 + n * 16 + fr;
          float dist = sqrow[rl] + sq[bcol + cl] - 2.0f * acc[m][n][q];
          float sv = ((brow + rl) == (bcol + cl)) ? 0.0f : __expf(-fmaxf(dist, 0.0f));
          simf[rl * 65 + cl] = sv;
        }
    __syncthreads();
    {
      const int c0 = wid * 16;
#pragma unroll
      for (int c = 0; c < 16; ++c) {
        float v = simf[lane * 65 + c0 + c];
        TOPK_INSERT(tv, ti, v, bcol + c0 + c);
      }
    }
    __syncthreads();
  }
#pragma unroll
  for (int s = 0; s < 10; ++s) {
    simf[(lane * 4 + wid) * 20 + s * 2]     = tv[s];
    simf[(lane * 4 + wid) * 20 + s * 2 + 1] = __int_as_float(ti[s]);
  }
  __syncthreads();
  if (t < 64) {
    float mv[10]; int mi[10];
#pragma unroll
    for (int s = 0; s < 10; ++s) { mv[s] = -INFINITY; mi[s] = 0x7fffffff; }
#pragma unroll
    for (int p = 0; p < 4; ++p)
#pragma unroll
      for (int s = 0; s < 10; ++s) {
        float v = simf[(t * 4 + p) * 20 + s * 2];
        int idx = __float_as_int(simf[(t * 4 + p) * 20 + s * 2 + 1]);
        TOPK_INSERT(mv, mi, v, idx);
      }
    float* orow = out + (size_t)(brow + t) * NROWS;
#pragma unroll
    for (int s = 0; s < 10; ++s) orow[mi[s]] = 1.0f;
  }
}

extern "C" void kernel_launch(void* const* d_in, const int* in_sizes, int n_in,
                              void* d_out, int out_size, void* d_ws, size_t ws_size,
                              hipStream_t stream) {
  const float* f = (const float*)d_in[0];
  float* out = (float*)d_out;

  const size_t sq_bytes   = (size_t)NROWS * sizeof(float);          // 49152
  const size_t fbf_bytes  = (size_t)NROWS * DIM * sizeof(unsigned short);
  const size_t part_bytes = (size_t)NROWS * NC * 10 * sizeof(float2);

  float* sq = (float*)d_ws;
  unsigned short* fbf = (unsigned short*)((char*)d_ws + sq_bytes);
  float2* part = (float2*)((char*)d_ws + sq_bytes + fbf_bytes);

  if (ws_size >= sq_bytes + fbf_bytes + part_bytes) {
    prep_kernel<<<NROWS / 4, 256, 0, stream>>>(f, sq, fbf);
    gram_topk<<<dim3(NROWS / BM, NC), 256, 0, stream>>>(fbf, sq, part, out);
    merge_scatter<<<NROWS / 128, 256, 0, stream>>>(part, out);
  } else if (ws_size >= sq_bytes + fbf_bytes) {
    prep_kernel<<<NROWS / 4, 256, 0, stream>>>(f, sq, fbf);
    knn_fallback<<<NROWS / 64, 256, 0, stream>>>(fbf, sq, out);
  }
}

// Round 5
// 2409.728 us; speedup vs baseline: 1.1482x; 1.1482x over previous
//
#include <hip/hip_runtime.h>
#include <hip/hip_bf16.h>
#include <stdint.h>

#define NROWS 12288
#define DIM   512
#define KNBR  10

// gram_topk geometry
#define NC    8            // column chunks
#define CHUNK (NROWS / NC) // 1536
#define BM    128
#define BN    128
#define BK    32
#define CT    (CHUNK / BN) // 12 col-tiles per block

typedef __attribute__((ext_vector_type(8))) short s16x8;
typedef __attribute__((ext_vector_type(4))) float f32x4;
typedef unsigned int u32;

static __device__ __forceinline__ unsigned short f2bf(float x) {
  __hip_bfloat16 b = __float2bfloat16(x);
  return *reinterpret_cast<unsigned short*>(&b);
}

static __device__ __forceinline__ void gload16(const void* g, void* l) {
  __builtin_amdgcn_global_load_lds(
      (const __attribute__((address_space(1))) u32*)g,
      (__attribute__((address_space(3))) u32*)l, 16, 0, 0);
}

// Stable top-k insert: keeps list sorted by (value desc, index asc).
#define TOPK_INSERT(TV, TI, V, IDX)                                              \
  do {                                                                           \
    float _v = (V); int _i = (IDX);                                              \
    if (_v > TV[9] || (_v == TV[9] && _i < TI[9])) {                             \
      TV[9] = _v; TI[9] = _i;                                                    \
      _Pragma("unroll")                                                          \
      for (int _s = 9; _s > 0; --_s) {                                           \
        bool _sw = (TV[_s] > TV[_s-1]) ||                                        \
                   (TV[_s] == TV[_s-1] && TI[_s] < TI[_s-1]);                    \
        if (_sw) {                                                               \
          float _tf = TV[_s]; TV[_s] = TV[_s-1]; TV[_s-1] = _tf;                 \
          int   _ti = TI[_s]; TI[_s] = TI[_s-1]; TI[_s-1] = _ti;                 \
        }                                                                        \
      }                                                                          \
    }                                                                            \
  } while (0)

// ---------------- Kernel 1: norms + bf16 conversion ----------------
__global__ __launch_bounds__(256) void prep_kernel(
    const float* __restrict__ f, float* __restrict__ sq,
    unsigned short* __restrict__ fbf) {
  const int wid = threadIdx.x >> 6;
  const int lane = threadIdx.x & 63;
  const int row = blockIdx.x * 4 + wid;
  const float4* fr = (const float4*)(f + (size_t)row * DIM);
  ushort4* br = (ushort4*)(fbf + (size_t)row * DIM);
  float s = 0.f;
#pragma unroll
  for (int u = 0; u < 2; ++u) {
    float4 v = fr[u * 64 + lane];
    s += v.x * v.x + v.y * v.y + v.z * v.z + v.w * v.w;
    ushort4 h;
    h.x = f2bf(v.x); h.y = f2bf(v.y); h.z = f2bf(v.z); h.w = f2bf(v.w);
    br[u * 64 + lane] = h;
  }
#pragma unroll
  for (int off = 32; off; off >>= 1) s += __shfl_down(s, off);
  if (lane == 0) sq[row] = s;
}

// ---------------- Kernel 2: 128x128 MFMA gram + chunked top-10 ----------------
// grid (96, NC). Block (rt, ch): rows rt*128..+128 x cols ch*CHUNK..+CHUNK.
//
// REGISTER-BUDGET NOTE (rounds 2-4 post-mortems):
//   (256,3)  -> cap ~170, heuristic chose 84 VGPR  -> full acc spill, 9.9 GB scratch
//   (256)    -> heuristic chose 160 VGPR           -> half acc spill, 4.8 GB scratch
//   (256,2)  -> explicit 2 waves/EU, cap 256 VGPR  -> live set (~220) fits, no spill
__global__ __launch_bounds__(256, 2) void gram_topk(
    const unsigned short* __restrict__ fbf, const float* __restrict__ sq,
    float2* __restrict__ part, float* __restrict__ out) {
  // LDS: [0,8192) A [4][128][8] bf16 ; [8192,16384) B ; [16384,+16768) slab [32][131] f32
  __shared__ __align__(16) char smem[33152];
  __shared__ float sqr[BM];
  __shared__ float sqc[BN];

  const int t = threadIdx.x;
  const int lane = t & 63, wid = t >> 6;
  const int wr = wid >> 1, wc = wid & 1;     // wave -> 64x64 quadrant
  const int fr = lane & 15, kg = lane >> 4;  // MFMA fragment coords
  const int brow = blockIdx.x * BM;
  const int chunk = blockIdx.y;

  // Zero-fill this block's slice of the output.
  {
    const int bid = blockIdx.y * 96 + blockIdx.x;          // 0..767
    const int per = NROWS * NROWS / (96 * NC) / 4;         // f32x4 per block
    f32x4* o4 = (f32x4*)out + (size_t)bid * per;
    f32x4 z = {0.f, 0.f, 0.f, 0.f};
    for (int i = t; i < per; i += 256) o4[i] = z;
  }
  if (t < BM) sqr[t] = sq[brow + t];

  short* Abuf = (short*)smem;
  short* Bbuf = (short*)(smem + 8192);
  float* slab = (float*)(smem + 16384);

  // per-thread partial top-10: thread owns row rt2 = t>>1, col-half h = t&1
  float tv[10]; int ti[10];
#pragma unroll
  for (int s = 0; s < 10; ++s) { tv[s] = -INFINITY; ti[s] = 0x7fffffff; }
  const int rt2 = t >> 1, h = t & 1;
  const int mneed = (rt2 >> 4) & 3;
  const int srow = ((rt2 >> 6) << 4) + (rt2 & 15);

  for (int ct = 0; ct < CT; ++ct) {
    const int bcol = chunk * CHUNK + ct * BN;
    if (t < BN) sqc[t] = sq[bcol + t];   // covered by first K-step barrier

    f32x4 acc[4][4];
#pragma unroll
    for (int m = 0; m < 4; ++m)
#pragma unroll
      for (int n = 0; n < 4; ++n)
#pragma unroll
        for (int q = 0; q < 4; ++q) acc[m][n][q] = 0.f;

    for (int kt = 0; kt < DIM; kt += BK) {
      // stage A,B tiles: [4 kgroups][128 rows][8 bf16], 512x16B chunks each
#pragma unroll
      for (int i = 0; i < 2; ++i) {
        const int c = i * 256 + t;
        const int row = c & 127, ckg = c >> 7;
        gload16(&fbf[(size_t)(brow + row) * DIM + kt + ckg * 8],
                smem + (i * 256 + wid * 64) * 16);
        gload16(&fbf[(size_t)(bcol + row) * DIM + kt + ckg * 8],
                smem + 8192 + (i * 256 + wid * 64) * 16);
      }
      __syncthreads();

      s16x8 a[4], b[4];
#pragma unroll
      for (int m = 0; m < 4; ++m)
        a[m] = *(const s16x8*)&Abuf[(kg * 128 + wr * 64 + m * 16 + fr) * 8];
#pragma unroll
      for (int n = 0; n < 4; ++n)
        b[n] = *(const s16x8*)&Bbuf[(kg * 128 + wc * 64 + n * 16 + fr) * 8];
#pragma unroll
      for (int m = 0; m < 4; ++m)
#pragma unroll
        for (int n = 0; n < 4; ++n)
          acc[m][n] = __builtin_amdgcn_mfma_f32_16x16x32_bf16(a[m], b[n], acc[m][n], 0, 0, 0);
      __syncthreads();
    }

    // epilogue: 4 slabs of 32 rows x 128 cols; sim -> LDS -> stable scan.
#pragma unroll
    for (int m = 0; m < 4; ++m) {
#pragma unroll
      for (int n = 0; n < 4; ++n)
#pragma unroll
        for (int q = 0; q < 4; ++q) {
          const int rl = kg * 4 + q;            // 0..15 within band
          const int tr = wr * 64 + m * 16 + rl; // tile row
          const int tc = wc * 64 + n * 16 + fr; // tile col
          const float dist = sqr[tr] + sqc[tc] - 2.0f * acc[m][n][q];
          const float sv = ((brow + tr) == (bcol + tc)) ? 0.0f
                          : __expf(-fmaxf(dist, 0.0f));
          slab[(wr * 16 + rl) * 131 + tc] = sv;
        }
      __syncthreads();
      if (mneed == m) {
#pragma unroll
        for (int c = 0; c < 64; ++c) {
          const float v = slab[srow * 131 + h * 64 + c];
          TOPK_INSERT(tv, ti, v, bcol + h * 64 + c);
        }
      }
      __syncthreads();
    }
  }

  // merge the two half-lists per row, write chunk list to ws
  float2* plist = (float2*)smem;  // 256*10*8 = 20480 B, overlays dead A/B/slab
  __syncthreads();
#pragma unroll
  for (int s = 0; s < 10; ++s)
    plist[t * 10 + s] = make_float2(tv[s], __int_as_float(ti[s]));
  __syncthreads();
  if (t < BM) {
    float mv[10]; int mi[10];
#pragma unroll
    for (int s = 0; s < 10; ++s) { mv[s] = -INFINITY; mi[s] = 0x7fffffff; }
#pragma unroll
    for (int p = 0; p < 2; ++p)
#pragma unroll
      for (int s = 0; s < 10; ++s) {
        const float2 e = plist[(t * 2 + p) * 10 + s];
        TOPK_INSERT(mv, mi, e.x, __float_as_int(e.y));
      }
    float2* dst = part + ((size_t)(brow + t) * NC + chunk) * 10;
#pragma unroll
    for (int s = 0; s < 10; ++s) dst[s] = make_float2(mv[s], __int_as_float(mi[s]));
  }
}

// ---------------- Kernel 3: merge NC chunk lists per row, scatter ones ----------------
__global__ __launch_bounds__(256) void merge_scatter(
    const float2* __restrict__ part, float* __restrict__ out) {
  const int t = threadIdx.x;
  if (t >= 128) return;
  const int r = blockIdx.x * 128 + t;
  float mv[10]; int mi[10];
#pragma unroll
  for (int s = 0; s < 10; ++s) { mv[s] = -INFINITY; mi[s] = 0x7fffffff; }
  const float2* p = part + (size_t)r * NC * 10;
#pragma unroll
  for (int c = 0; c < NC * 10; ++c)
    TOPK_INSERT(mv, mi, p[c].x, __float_as_int(p[c].y));
  float* orow = out + (size_t)r * NROWS;
#pragma unroll
  for (int s = 0; s < 10; ++s) orow[mi[s]] = 1.0f;
}

// ---------------- Fallback (round-1 single-kernel path, needs only 12.6 MB ws) ----------------
__global__ __launch_bounds__(256) void knn_fallback(
    const unsigned short* __restrict__ fbf, const float* __restrict__ sq,
    float* __restrict__ out) {
  __shared__ short aT[64][32];
  __shared__ short bT[64][32];
  __shared__ float simf[5120];
  __shared__ float sqrow[64];

  const int t = threadIdx.x;
  const int lane = t & 63, wid = t >> 6;
  const int wr = wid >> 1, wc = wid & 1;
  const int fr = lane & 15, kg = lane >> 4;
  const int brow = blockIdx.x * 64;

  {
    f32x4* o4 = (f32x4*)(out + (size_t)brow * NROWS);
    const int total4 = 64 * NROWS / 4;
    f32x4 z = {0.f, 0.f, 0.f, 0.f};
    for (int i = t; i < total4; i += 256) o4[i] = z;
  }
  if (t < 64) sqrow[t] = sq[brow + t];

  float tv[10]; int ti[10];
#pragma unroll
  for (int s = 0; s < 10; ++s) { tv[s] = -INFINITY; ti[s] = 0x7fffffff; }
  const int sstage_r = t >> 2;
  const int sstage_k = (t & 3) * 8;

  for (int ctile = 0; ctile < NROWS / 64; ++ctile) {
    const int bcol = ctile * 64;
    f32x4 acc[2][2];
#pragma unroll
    for (int m = 0; m < 2; ++m)
#pragma unroll
      for (int n = 0; n < 2; ++n)
#pragma unroll
        for (int q = 0; q < 4; ++q) acc[m][n][q] = 0.f;

    for (int kt = 0; kt < DIM; kt += 32) {
      *(s16x8*)&aT[sstage_r][sstage_k] =
          *(const s16x8*)&fbf[(size_t)(brow + sstage_r) * DIM + kt + sstage_k];
      *(s16x8*)&bT[sstage_r][sstage_k] =
          *(const s16x8*)&fbf[(size_t)(bcol + sstage_r) * DIM + kt + sstage_k];
      __syncthreads();
      s16x8 a0 = *(const s16x8*)&aT[wr * 32 + fr][kg * 8];
      s16x8 a1 = *(const s16x8*)&aT[wr * 32 + 16 + fr][kg * 8];
      s16x8 b0 = *(const s16x8*)&bT[wc * 32 + fr][kg * 8];
      s16x8 b1 = *(const s16x8*)&bT[wc * 32 + 16 + fr][kg * 8];
      acc[0][0] = __builtin_amdgcn_mfma_f32_16x16x32_bf16(a0, b0, acc[0][0], 0, 0, 0);
      acc[0][1] = __builtin_amdgcn_mfma_f32_16x16x32_bf16(a0, b1, acc[0][1], 0, 0, 0);
      acc[1][0] = __builtin_amdgcn_mfma_f32_16x16x32_bf16(a1, b0, acc[1][0], 0, 0, 0);
      acc[1][1] = __builtin_amdgcn_mfma_f32_16x16x32_bf16(a1, b1, acc[1][1], 0, 0, 0);
      __syncthreads();
    }
#pragma unroll
    for (int m = 0; m < 2; ++m)
#pragma unroll
      for (int n = 0; n < 2; ++n)
#pragma unroll
        for (int q = 0; q < 4; ++q) {
          int rl = wr * 32 + m * 16 + kg * 4 + q;
          int cl = wc * 32 + n * 16 + fr;
          float dist = sqrow[rl] + sq[bcol + cl] - 2.0f * acc[m][n][q];
          float sv = ((brow + rl) == (bcol + cl)) ? 0.0f : __expf(-fmaxf(dist, 0.0f));
          simf[rl * 65 + cl] = sv;
        }
    __syncthreads();
    {
      const int c0 = wid * 16;
#pragma unroll
      for (int c = 0; c < 16; ++c) {
        float v = simf[lane * 65 + c0 + c];
        TOPK_INSERT(tv, ti, v, bcol + c0 + c);
      }
    }
    __syncthreads();
  }
#pragma unroll
  for (int s = 0; s < 10; ++s) {
    simf[(lane * 4 + wid) * 20 + s * 2]     = tv[s];
    simf[(lane * 4 + wid) * 20 + s * 2 + 1] = __int_as_float(ti[s]);
  }
  __syncthreads();
  if (t < 64) {
    float mv[10]; int mi[10];
#pragma unroll
    for (int s = 0; s < 10; ++s) { mv[s] = -INFINITY; mi[s] = 0x7fffffff; }
#pragma unroll
    for (int p = 0; p < 4; ++p)
#pragma unroll
      for (int s = 0; s < 10; ++s) {
        float v = simf[(t * 4 + p) * 20 + s * 2];
        int idx = __float_as_int(simf[(t * 4 + p) * 20 + s * 2 + 1]);
        TOPK_INSERT(mv, mi, v, idx);
      }
    float* orow = out + (size_t)(brow + t) * NROWS;
#pragma unroll
    for (int s = 0; s < 10; ++s) orow[mi[s]] = 1.0f;
  }
}

extern "C" void kernel_launch(void* const* d_in, const int* in_sizes, int n_in,
                              void* d_out, int out_size, void* d_ws, size_t ws_size,
                              hipStream_t stream) {
  const float* f = (const float*)d_in[0];
  float* out = (float*)d_out;

  const size_t sq_bytes   = (size_t)NROWS * sizeof(float);          // 49152
  const size_t fbf_bytes  = (size_t)NROWS * DIM * sizeof(unsigned short);
  const size_t part_bytes = (size_t)NROWS * NC * 10 * sizeof(float2);

  float* sq = (float*)d_ws;
  unsigned short* fbf = (unsigned short*)((char*)d_ws + sq_bytes);
  float2* part = (float2*)((char*)d_ws + sq_bytes + fbf_bytes);

  if (ws_size >= sq_bytes + fbf_bytes + part_bytes) {
    prep_kernel<<<NROWS / 4, 256, 0, stream>>>(f, sq, fbf);
    gram_topk<<<dim3(NROWS / BM, NC), 256, 0, stream>>>(fbf, sq, part, out);
    merge_scatter<<<NROWS / 128, 256, 0, stream>>>(part, out);
  } else if (ws_size >= sq_bytes + fbf_bytes) {
    prep_kernel<<<NROWS / 4, 256, 0, stream>>>(f, sq, fbf);
    knn_fallback<<<NROWS / 64, 256, 0, stream>>>(fbf, sq, out);
  }
}

// Round 6
// 1797.673 us; speedup vs baseline: 1.5391x; 1.3405x over previous
//
#include <hip/hip_runtime.h>
#include <hip/hip_bf16.h>
#include <stdint.h>

#define NROWS 12288
#define DIM   512
#define KNBR  10

// gram_topk geometry
#define NC    8            // column chunks
#define CHUNK (NROWS / NC) // 1536
#define BM    128
#define BN    64
#define BK    32
#define CT    (CHUNK / BN) // 24 col-tiles per block

typedef __attribute__((ext_vector_type(8))) short s16x8;
typedef __attribute__((ext_vector_type(4))) float f32x4;
typedef unsigned int u32;

static __device__ __forceinline__ unsigned short f2bf(float x) {
  __hip_bfloat16 b = __float2bfloat16(x);
  return *reinterpret_cast<unsigned short*>(&b);
}

static __device__ __forceinline__ void gload16(const void* g, void* l) {
  __builtin_amdgcn_global_load_lds(
      (const __attribute__((address_space(1))) u32*)g,
      (__attribute__((address_space(3))) u32*)l, 16, 0, 0);
}

// Stable top-k insert: keeps list sorted by (value desc, index asc).
#define TOPK_INSERT(TV, TI, V, IDX)                                              \
  do {                                                                           \
    float _v = (V); int _i = (IDX);                                              \
    if (_v > TV[9] || (_v == TV[9] && _i < TI[9])) {                             \
      TV[9] = _v; TI[9] = _i;                                                    \
      _Pragma("unroll")                                                          \
      for (int _s = 9; _s > 0; --_s) {                                           \
        bool _sw = (TV[_s] > TV[_s-1]) ||                                        \
                   (TV[_s] == TV[_s-1] && TI[_s] < TI[_s-1]);                    \
        if (_sw) {                                                               \
          float _tf = TV[_s]; TV[_s] = TV[_s-1]; TV[_s-1] = _tf;                 \
          int   _ti = TI[_s]; TI[_s] = TI[_s-1]; TI[_s-1] = _ti;                 \
        }                                                                        \
      }                                                                          \
    }                                                                            \
  } while (0)

// ---------------- Kernel 1: norms + bf16 conversion ----------------
__global__ __launch_bounds__(256) void prep_kernel(
    const float* __restrict__ f, float* __restrict__ sq,
    unsigned short* __restrict__ fbf) {
  const int wid = threadIdx.x >> 6;
  const int lane = threadIdx.x & 63;
  const int row = blockIdx.x * 4 + wid;
  const float4* fr = (const float4*)(f + (size_t)row * DIM);
  ushort4* br = (ushort4*)(fbf + (size_t)row * DIM);
  float s = 0.f;
#pragma unroll
  for (int u = 0; u < 2; ++u) {
    float4 v = fr[u * 64 + lane];
    s += v.x * v.x + v.y * v.y + v.z * v.z + v.w * v.w;
    ushort4 h;
    h.x = f2bf(v.x); h.y = f2bf(v.y); h.z = f2bf(v.z); h.w = f2bf(v.w);
    br[u * 64 + lane] = h;
  }
#pragma unroll
  for (int off = 32; off; off >>= 1) s += __shfl_down(s, off);
  if (lane == 0) sq[row] = s;
}

// ---------------- Kernel 2: 128x64 MFMA gram + chunked top-10 ----------------
// grid (96, NC). Block (rt, ch): rows rt*128..+128 x cols ch*CHUNK..+CHUNK,
// iterated in 24 tiles of 64 cols. Per-wave sub-tile is 64x32 -> acc[4][2]
// (32 VGPR). Rounds 2-5 showed the allocator grants this kernel ~128 VGPR
// no matter what launch bounds we request; acc[4][4] (64 VGPR) spilled 5-10 GB
// of scratch every round. Shrinking the live set below 128 is the fix.
__global__ __launch_bounds__(256) void gram_topk(
    const unsigned short* __restrict__ fbf, const float* __restrict__ sq,
    float2* __restrict__ part, float* __restrict__ out) {
  // LDS: [0,8192) A [4][128][8] bf16 ; [8192,12288) B [4][64][8] bf16 ;
  //      [12288,20864) slab [32][67] f32. plist (20480 B) overlays at end.
  __shared__ __align__(16) char smem[20864];
  __shared__ float sqr[BM];
  __shared__ float sqc[BN];

  const int t = threadIdx.x;
  const int lane = t & 63, wid = t >> 6;
  const int wr = wid >> 1, wc = wid & 1;     // wave -> 64-row half, 32-col half
  const int fr = lane & 15, kg = lane >> 4;  // MFMA fragment coords
  const int brow = blockIdx.x * BM;
  const int chunk = blockIdx.y;

  // Zero-fill this block's slice of the output.
  {
    const int bid = blockIdx.y * 96 + blockIdx.x;          // 0..767
    const int per = NROWS * NROWS / (96 * NC) / 4;         // f32x4 per block
    f32x4* o4 = (f32x4*)out + (size_t)bid * per;
    f32x4 z = {0.f, 0.f, 0.f, 0.f};
    for (int i = t; i < per; i += 256) o4[i] = z;
  }
  if (t < BM) sqr[t] = sq[brow + t];

  short* Abuf = (short*)smem;
  short* Bbuf = (short*)(smem + 8192);
  float* slab = (float*)(smem + 12288);

  // per-thread partial top-10: thread owns row rt2 = t>>1, col-half h = t&1
  float tv[10]; int ti[10];
#pragma unroll
  for (int s = 0; s < 10; ++s) { tv[s] = -INFINITY; ti[s] = 0x7fffffff; }
  const int rt2 = t >> 1, h = t & 1;
  const int mneed = (rt2 >> 4) & 3;
  const int srow = ((rt2 >> 6) << 4) + (rt2 & 15);

  for (int ct = 0; ct < CT; ++ct) {
    const int bcol = chunk * CHUNK + ct * BN;
    if (t < BN) sqc[t] = sq[bcol + t];   // covered by first K-step barrier

    f32x4 acc[4][2];
#pragma unroll
    for (int m = 0; m < 4; ++m)
#pragma unroll
      for (int n = 0; n < 2; ++n)
#pragma unroll
        for (int q = 0; q < 4; ++q) acc[m][n][q] = 0.f;

    for (int kt = 0; kt < DIM; kt += BK) {
      // stage A [4 kg][128 rows][8 bf16] (512 x 16B) and B [4 kg][64][8] (256 x 16B)
#pragma unroll
      for (int i = 0; i < 2; ++i) {
        const int c = i * 256 + t;
        const int row = c & 127, ckg = c >> 7;
        gload16(&fbf[(size_t)(brow + row) * DIM + kt + ckg * 8],
                smem + (i * 256 + wid * 64) * 16);
      }
      {
        const int row = t & 63, ckg = t >> 6;
        gload16(&fbf[(size_t)(bcol + row) * DIM + kt + ckg * 8],
                smem + 8192 + (wid * 64) * 16);
      }
      __syncthreads();

      s16x8 a[4], b[2];
#pragma unroll
      for (int m = 0; m < 4; ++m)
        a[m] = *(const s16x8*)&Abuf[(kg * 128 + wr * 64 + m * 16 + fr) * 8];
#pragma unroll
      for (int n = 0; n < 2; ++n)
        b[n] = *(const s16x8*)&Bbuf[(kg * 64 + wc * 32 + n * 16 + fr) * 8];
#pragma unroll
      for (int m = 0; m < 4; ++m)
#pragma unroll
        for (int n = 0; n < 2; ++n)
          acc[m][n] = __builtin_amdgcn_mfma_f32_16x16x32_bf16(a[m], b[n], acc[m][n], 0, 0, 0);
      __syncthreads();
    }

    // epilogue: 4 slabs of 32 rows x 64 cols; sim -> LDS -> stable scan.
#pragma unroll
    for (int m = 0; m < 4; ++m) {
#pragma unroll
      for (int n = 0; n < 2; ++n)
#pragma unroll
        for (int q = 0; q < 4; ++q) {
          const int rl = kg * 4 + q;            // 0..15 within band
          const int tr = wr * 64 + m * 16 + rl; // tile row
          const int tc = wc * 32 + n * 16 + fr; // tile col
          const float dist = sqr[tr] + sqc[tc] - 2.0f * acc[m][n][q];
          const float sv = ((brow + tr) == (bcol + tc)) ? 0.0f
                          : __expf(-fmaxf(dist, 0.0f));
          slab[(wr * 16 + rl) * 67 + tc] = sv;
        }
      __syncthreads();
      if (mneed == m) {
#pragma unroll
        for (int c = 0; c < 32; ++c) {
          const float v = slab[srow * 67 + h * 32 + c];
          TOPK_INSERT(tv, ti, v, bcol + h * 32 + c);
        }
      }
      __syncthreads();
    }
  }

  // merge the two half-lists per row, write chunk list to ws
  float2* plist = (float2*)smem;  // 256*10*8 = 20480 B, overlays dead A/B/slab
  __syncthreads();
#pragma unroll
  for (int s = 0; s < 10; ++s)
    plist[t * 10 + s] = make_float2(tv[s], __int_as_float(ti[s]));
  __syncthreads();
  if (t < BM) {
    float mv[10]; int mi[10];
#pragma unroll
    for (int s = 0; s < 10; ++s) { mv[s] = -INFINITY; mi[s] = 0x7fffffff; }
#pragma unroll
    for (int p = 0; p < 2; ++p)
#pragma unroll
      for (int s = 0; s < 10; ++s) {
        const float2 e = plist[(t * 2 + p) * 10 + s];
        TOPK_INSERT(mv, mi, e.x, __float_as_int(e.y));
      }
    float2* dst = part + ((size_t)(brow + t) * NC + chunk) * 10;
#pragma unroll
    for (int s = 0; s < 10; ++s) dst[s] = make_float2(mv[s], __int_as_float(mi[s]));
  }
}

// ---------------- Kernel 3: merge NC chunk lists per row, scatter ones ----------------
__global__ __launch_bounds__(256) void merge_scatter(
    const float2* __restrict__ part, float* __restrict__ out) {
  const int t = threadIdx.x;
  if (t >= 128) return;
  const int r = blockIdx.x * 128 + t;
  float mv[10]; int mi[10];
#pragma unroll
  for (int s = 0; s < 10; ++s) { mv[s] = -INFINITY; mi[s] = 0x7fffffff; }
  const float2* p = part + (size_t)r * NC * 10;
#pragma unroll
  for (int c = 0; c < NC * 10; ++c)
    TOPK_INSERT(mv, mi, p[c].x, __float_as_int(p[c].y));
  float* orow = out + (size_t)r * NROWS;
#pragma unroll
  for (int s = 0; s < 10; ++s) orow[mi[s]] = 1.0f;
}

// ---------------- Fallback (round-1 single-kernel path, needs only 12.6 MB ws) ----------------
__global__ __launch_bounds__(256) void knn_fallback(
    const unsigned short* __restrict__ fbf, const float* __restrict__ sq,
    float* __restrict__ out) {
  __shared__ short aT[64][32];
  __shared__ short bT[64][32];
  __shared__ float simf[5120];
  __shared__ float sqrow[64];

  const int t = threadIdx.x;
  const int lane = t & 63, wid = t >> 6;
  const int wr = wid >> 1, wc = wid & 1;
  const int fr = lane & 15, kg = lane >> 4;
  const int brow = blockIdx.x * 64;

  {
    f32x4* o4 = (f32x4*)(out + (size_t)brow * NROWS);
    const int total4 = 64 * NROWS / 4;
    f32x4 z = {0.f, 0.f, 0.f, 0.f};
    for (int i = t; i < total4; i += 256) o4[i] = z;
  }
  if (t < 64) sqrow[t] = sq[brow + t];

  float tv[10]; int ti[10];
#pragma unroll
  for (int s = 0; s < 10; ++s) { tv[s] = -INFINITY; ti[s] = 0x7fffffff; }
  const int sstage_r = t >> 2;
  const int sstage_k = (t & 3) * 8;

  for (int ctile = 0; ctile < NROWS / 64; ++ctile) {
    const int bcol = ctile * 64;
    f32x4 acc[2][2];
#pragma unroll
    for (int m = 0; m < 2; ++m)
#pragma unroll
      for (int n = 0; n < 2; ++n)
#pragma unroll
        for (int q = 0; q < 4; ++q) acc[m][n][q] = 0.f;

    for (int kt = 0; kt < DIM; kt += 32) {
      *(s16x8*)&aT[sstage_r][sstage_k] =
          *(const s16x8*)&fbf[(size_t)(brow + sstage_r) * DIM + kt + sstage_k];
      *(s16x8*)&bT[sstage_r][sstage_k] =
          *(const s16x8*)&fbf[(size_t)(bcol + sstage_r) * DIM + kt + sstage_k];
      __syncthreads();
      s16x8 a0 = *(const s16x8*)&aT[wr * 32 + fr][kg * 8];
      s16x8 a1 = *(const s16x8*)&aT[wr * 32 + 16 + fr][kg * 8];
      s16x8 b0 = *(const s16x8*)&bT[wc * 32 + fr][kg * 8];
      s16x8 b1 = *(const s16x8*)&bT[wc * 32 + 16 + fr][kg * 8];
      acc[0][0] = __builtin_amdgcn_mfma_f32_16x16x32_bf16(a0, b0, acc[0][0], 0, 0, 0);
      acc[0][1] = __builtin_amdgcn_mfma_f32_16x16x32_bf16(a0, b1, acc[0][1], 0, 0, 0);
      acc[1][0] = __builtin_amdgcn_mfma_f32_16x16x32_bf16(a1, b0, acc[1][0], 0, 0, 0);
      acc[1][1] = __builtin_amdgcn_mfma_f32_16x16x32_bf16(a1, b1, acc[1][1], 0, 0, 0);
      __syncthreads();
    }
#pragma unroll
    for (int m = 0; m < 2; ++m)
#pragma unroll
      for (int n = 0; n < 2; ++n)
#pragma unroll
        for (int q = 0; q < 4; ++q) {
          int rl = wr * 32 + m * 16 + kg * 4 + q;
          int cl = wc * 32 + n * 16 + fr;
          float dist = sqrow[rl] + sq[bcol + cl] - 2.0f * acc[m][n][q];
          float sv = ((brow + rl) == (bcol + cl)) ? 0.0f : __expf(-fmaxf(dist, 0.0f));
          simf[rl * 65 + cl] = sv;
        }
    __syncthreads();
    {
      const int c0 = wid * 16;
#pragma unroll
      for (int c = 0; c < 16; ++c) {
        float v = simf[lane * 65 + c0 + c];
        TOPK_INSERT(tv, ti, v, bcol + c0 + c);
      }
    }
    __syncthreads();
  }
#pragma unroll
  for (int s = 0; s < 10; ++s) {
    simf[(lane * 4 + wid) * 20 + s * 2]     = tv[s];
    simf[(lane * 4 + wid) * 20 + s * 2 + 1] = __int_as_float(ti[s]);
  }
  __syncthreads();
  if (t < 64) {
    float mv[10]; int mi[10];
#pragma unroll
    for (int s = 0; s < 10; ++s) { mv[s] = -INFINITY; mi[s] = 0x7fffffff; }
#pragma unroll
    for (int p = 0; p < 4; ++p)
#pragma unroll
      for (int s = 0; s < 10; ++s) {
        float v = simf[(t * 4 + p) * 20 + s * 2];
        int idx = __float_as_int(simf[(t * 4 + p) * 20 + s * 2 + 1]);
        TOPK_INSERT(mv, mi, v, idx);
      }
    float* orow = out + (size_t)(brow + t) * NROWS;
#pragma unroll
    for (int s = 0; s < 10; ++s) orow[mi[s]] = 1.0f;
  }
}

extern "C" void kernel_launch(void* const* d_in, const int* in_sizes, int n_in,
                              void* d_out, int out_size, void* d_ws, size_t ws_size,
                              hipStream_t stream) {
  const float* f = (const float*)d_in[0];
  float* out = (float*)d_out;

  const size_t sq_bytes   = (size_t)NROWS * sizeof(float);          // 49152
  const size_t fbf_bytes  = (size_t)NROWS * DIM * sizeof(unsigned short);
  const size_t part_bytes = (size_t)NROWS * NC * 10 * sizeof(float2);

  float* sq = (float*)d_ws;
  unsigned short* fbf = (unsigned short*)((char*)d_ws + sq_bytes);
  float2* part = (float2*)((char*)d_ws + sq_bytes + fbf_bytes);

  if (ws_size >= sq_bytes + fbf_bytes + part_bytes) {
    prep_kernel<<<NROWS / 4, 256, 0, stream>>>(f, sq, fbf);
    gram_topk<<<dim3(NROWS / BM, NC), 256, 0, stream>>>(fbf, sq, part, out);
    merge_scatter<<<NROWS / 128, 256, 0, stream>>>(part, out);
  } else if (ws_size >= sq_bytes + fbf_bytes) {
    prep_kernel<<<NROWS / 4, 256, 0, stream>>>(f, sq, fbf);
    knn_fallback<<<NROWS / 64, 256, 0, stream>>>(fbf, sq, out);
  }
}